// Round 2
// baseline (1801.712 us; speedup 1.0000x reference)
//
#include <hip/hip_runtime.h>
#include <hip/hip_bf16.h>

#define HDIM 128
#define NREL 16
#define NBASES 8
#define TILE 64        // output rows per block (dst-tile)
#define LDSF 132       // fp32 row stride for A tile: 4-bank rotation per row
#define ELCAP 1536     // per-tile edge-list LDS capacity (mean 1024, 16 sigma)
#define PF 4           // prefetched edges per gather group (covers 128/bucket)
#define NTHREADS 512

typedef short bf16x8 __attribute__((ext_vector_type(8)));
typedef short s16x4 __attribute__((ext_vector_type(4)));
typedef float f32x4 __attribute__((ext_vector_type(4)));

static __device__ __forceinline__ short f2bf(float x) {
    __hip_bfloat16 b = __float2bfloat16(x);
    return *(short*)&b;
}
static __device__ __forceinline__ float bf2f(short u) {
    unsigned v = ((unsigned)(unsigned short)u) << 16;
    return __uint_as_float(v);
}

// ---------------- weight prep (fp32 in -> bf16 out) ----------------
// wt[r][o][i] = W_r[i][o] = sum_b wcomp[r][b] * basis[b][i][o]
__global__ void compute_wt(const float* __restrict__ basis,
                           const float* __restrict__ wcomp,
                           short* __restrict__ wt) {
    int ro = blockIdx.x;
    int r = ro >> 7, o = ro & 127;
    int i = threadIdx.x;
    float acc = 0.f;
#pragma unroll
    for (int b = 0; b < NBASES; ++b)
        acc += wcomp[r * NBASES + b] * basis[(b * HDIM + i) * HDIM + o];
    wt[(size_t)(r * HDIM + o) * HDIM + i] = f2bf(acc);
}

// lwT[o][i] = loop_w[i][o]  (fp32 -> bf16)
__global__ void transpose128(const float* __restrict__ in, short* __restrict__ out) {
    int o = blockIdx.x, i = threadIdx.x;
    out[o * HDIM + i] = f2bf(in[i * HDIM + o]);
}

// fp32 -> bf16 cast (vectorized)
__global__ void cast_bf16(const float* __restrict__ in, short* __restrict__ out, int n4) {
    for (int i = blockIdx.x * blockDim.x + threadIdx.x; i < n4; i += gridDim.x * blockDim.x) {
        f32x4 v = ((const f32x4*)in)[i];
        s16x4 o;
#pragma unroll
        for (int j = 0; j < 4; ++j) o[j] = f2bf(v[j]);
        ((s16x4*)out)[i] = o;
    }
}

__global__ void zero_i32(int* __restrict__ p, int n) {
    int i = blockIdx.x * blockDim.x + threadIdx.x;
    if (i < n) p[i] = 0;
}

// ---------------- bucket sort: (dst-tile, rel) buckets ----------------
__global__ __launch_bounds__(256) void hist_b(const int* __restrict__ dst,
                                              const int* __restrict__ rel, int n,
                                              int* __restrict__ cnt) {
    for (int i = blockIdx.x * blockDim.x + threadIdx.x; i < n; i += gridDim.x * blockDim.x) {
        int b = (dst[i] >> 6) * NREL + rel[i];
        atomicAdd(&cnt[b], 1);
    }
}

__global__ __launch_bounds__(1024) void scan_b(const int* __restrict__ cnt, int nb,
                                               int* __restrict__ off, int* __restrict__ cur) {
    __shared__ int part[1024];
    int t = threadIdx.x;
    int per = (nb + 1023) >> 10;
    int lo = t * per, hi = min(nb, lo + per);
    int s = 0;
    for (int i = lo; i < hi; ++i) s += cnt[i];
    part[t] = s;
    __syncthreads();
    for (int d = 1; d < 1024; d <<= 1) {
        int v = part[t];
        int u = (t >= d) ? part[t - d] : 0;
        __syncthreads();
        part[t] = v + u;
        __syncthreads();
    }
    int run = (t > 0) ? part[t - 1] : 0;
    for (int i = lo; i < hi; ++i) {
        off[i] = run; cur[i] = run;
        run += cnt[i];
    }
    if (t == 0) off[nb] = part[1023];
}

// pack: src (16 bits, n_ent < 65536) | (dst & 63) << 16
__global__ __launch_bounds__(256) void scatter_b(const int* __restrict__ src,
                                                 const int* __restrict__ dst,
                                                 const int* __restrict__ rel, int n,
                                                 int* __restrict__ cur,
                                                 int* __restrict__ edge_s) {
    for (int i = blockIdx.x * blockDim.x + threadIdx.x; i < n; i += gridDim.x * blockDim.x) {
        int d = dst[i];
        int b = (d >> 6) * NREL + rel[i];
        int p = atomicAdd(&cur[b], 1);
        edge_s[p] = (src[i] & 0xFFFF) | ((d & 63) << 16);
    }
}

// ---------------- fused RGCN layer (pipelined) ----------------
// Block = 64 output rows, 512 threads (8 waves: 2 row-halves x 4 col-quarters).
// Prologue: per-tile edge list (contiguous in edge_s) -> LDS once.
// Per relation r: zero A | ds_add prefetched h[src] rows (regs) | issue loads
// for bucket r+1 | barrier | MFMA(r). The random-gather latency of bucket r+1
// hides under MFMA(r) + zero(r+1): no exposed dependent-load chain remains.
// r==16 is the self-loop (A = h[tile rows], B = loop_w^T).
__global__ __launch_bounds__(NTHREADS, 2) void rgcn_layer(
    const short* __restrict__ h,      // bf16 [N][128]
    const short* __restrict__ wt,     // bf16 [16][o][i]
    const short* __restrict__ lwT,    // bf16 [o][i] = loop_w[i][o]
    const float* __restrict__ bias,   // fp32 [128]
    const int* __restrict__ off,      // [ntiles*16 + 1]
    const int* __restrict__ edge_s,   // packed src | dloc<<16, bucket-sorted
    short* __restrict__ out_bf,       // layer-1 output (bf16) or nullptr
    float* __restrict__ out_f,        // layer-2 output (fp32) or nullptr
    int N) {
    __shared__ __align__(16) float A[TILE * LDSF];
    __shared__ int elist[ELCAP];
    __shared__ int sOff[NREL + 1];

    int tile = blockIdx.x;
    int n0 = tile * TILE;
    int tid = threadIdx.x;
    int wave = tid >> 6, lane = tid & 63;
    int mq = (wave & 1) * 32;          // row half  (32 rows)
    int nq = (wave >> 1) * 32;         // col quarter (32 cols)
    int lr = lane & 15, quad = lane >> 4;
    int g = tid >> 4, lane16 = tid & 15;   // 32 gather groups x 16 lanes

    // ---- prologue: offsets + edge list into LDS (coalesced, once) ----
    if (tid <= NREL) sOff[tid] = off[tile * NREL + tid];
    __syncthreads();
    int base = sOff[0];
    int lim = min(sOff[NREL] - base, ELCAP);
    for (int i = tid; i < lim; i += NTHREADS) elist[i] = edge_s[base + i];
    __syncthreads();

    bf16x8 va[PF];
    int dl[PF];

    auto prefetch = [&](int r) {
        if (r < NREL) {
            int e0 = sOff[r], e1 = sOff[r + 1];
#pragma unroll
            for (int p = 0; p < PF; ++p) {
                int e = e0 + g + p * 32;
                if (e < e1) {
                    int pk = (e - base < ELCAP) ? elist[e - base] : edge_s[e];
                    dl[p] = (pk >> 16) & 63;
                    va[p] = *(const bf16x8*)(h + (size_t)(pk & 0xFFFF) * HDIM + lane16 * 8);
                } else dl[p] = -1;
            }
        } else {
            // self-loop rows
#pragma unroll
            for (int p = 0; p < PF; ++p) {
                int row = g + p * 32;
                if (row < TILE && n0 + row < N) {
                    dl[p] = row;
                    va[p] = *(const bf16x8*)(h + (size_t)(n0 + row) * HDIM + lane16 * 8);
                } else dl[p] = -1;
            }
        }
    };

    prefetch(0);

    f32x4 acc[2][2] = {};

    for (int r = 0; r <= NREL; ++r) {
        // B fragments for this relation (L2-hot), issued first
        const short* br = (r < NREL) ? (wt + (size_t)r * HDIM * HDIM) : lwT;
        bf16x8 b[4][2];
#pragma unroll
        for (int kk = 0; kk < 4; ++kk)
#pragma unroll
            for (int ni = 0; ni < 2; ++ni)
                b[kk][ni] = *(const bf16x8*)(br + (nq + ni * 16 + lr) * HDIM + kk * 32 + quad * 8);

        // zero A (A is free: prologue sync for r=0, end-of-body sync after)
        for (int i = tid; i < TILE * LDSF / 4; i += NTHREADS)
            ((f32x4*)A)[i] = (f32x4){0.f, 0.f, 0.f, 0.f};
        __syncthreads();

        // accumulate the prefetched rows (registers -> LDS atomics)
#pragma unroll
        for (int p = 0; p < PF; ++p) {
            if (dl[p] >= 0) {
                float* arow = A + dl[p] * LDSF + lane16 * 8;
#pragma unroll
                for (int c = 0; c < 8; ++c) atomicAdd(arow + c, bf2f(va[p][c]));
            }
        }
        // overflow fallback (bucket > PF*32 edges: essentially never)
        if (r < NREL) {
            int e0 = sOff[r], e1 = sOff[r + 1];
            for (int e = e0 + PF * 32 + g; e < e1; e += 32) {
                int pk = (e - base < ELCAP) ? elist[e - base] : edge_s[e];
                int s = pk & 0xFFFF, d2 = (pk >> 16) & 63;
                bf16x8 v = *(const bf16x8*)(h + (size_t)s * HDIM + lane16 * 8);
                float* arow = A + d2 * LDSF + lane16 * 8;
#pragma unroll
                for (int c = 0; c < 8; ++c) atomicAdd(arow + c, bf2f(v[c]));
            }
        }
        // issue next bucket's gather now; latency hides under MFMA below
        if (r < NREL) prefetch(r + 1);
        __syncthreads();

        // MFMA: acc += bf16(A) @ B_r
#pragma unroll
        for (int kk = 0; kk < 4; ++kk) {
            int kb = kk * 32 + quad * 8;
            bf16x8 a[2];
#pragma unroll
            for (int mi = 0; mi < 2; ++mi) {
                const float* ap = A + (mq + mi * 16 + lr) * LDSF + kb;
                f32x4 lo = *(const f32x4*)ap;
                f32x4 hi = *(const f32x4*)(ap + 4);
                bf16x8 av;
#pragma unroll
                for (int c = 0; c < 4; ++c) { av[c] = f2bf(lo[c]); av[c + 4] = f2bf(hi[c]); }
                a[mi] = av;
            }
#pragma unroll
            for (int mi = 0; mi < 2; ++mi)
#pragma unroll
                for (int ni = 0; ni < 2; ++ni)
                    acc[mi][ni] = __builtin_amdgcn_mfma_f32_16x16x32_bf16(a[mi], b[kk][ni], acc[mi][ni], 0, 0, 0);
        }
        __syncthreads();   // A consumed; next iteration may zero it
    }

    // epilogue: bias + relu, single non-atomic store
    // C/D: col = lane&15 (n), row = quad*4 + reg (m)  [m89]
#pragma unroll
    for (int mi = 0; mi < 2; ++mi) {
#pragma unroll
        for (int reg = 0; reg < 4; ++reg) {
            int gr = n0 + mq + mi * 16 + quad * 4 + reg;
            if (gr < N) {
#pragma unroll
                for (int ni = 0; ni < 2; ++ni) {
                    int n = nq + ni * 16 + lr;
                    float v = acc[mi][ni][reg] + bias[n];
                    v = v > 0.f ? v : 0.f;
                    if (out_bf) out_bf[(size_t)gr * HDIM + n] = f2bf(v);
                    else        out_f[(size_t)gr * HDIM + n] = v;
                }
            }
        }
    }
}

extern "C" void kernel_launch(void* const* d_in, const int* in_sizes, int n_in,
                              void* d_out, int out_size, void* d_ws, size_t ws_size,
                              hipStream_t stream) {
    const float* emb    = (const float*)d_in[0];
    const float* basis1 = (const float*)d_in[1];
    const float* wc1    = (const float*)d_in[2];
    const float* lw1    = (const float*)d_in[3];
    const float* bias1  = (const float*)d_in[4];
    const float* basis2 = (const float*)d_in[5];
    const float* wc2    = (const float*)d_in[6];
    const float* lw2    = (const float*)d_in[7];
    const float* bias2  = (const float*)d_in[8];
    const int* src = (const int*)d_in[9];
    const int* dst = (const int*)d_in[10];
    const int* rel = (const int*)d_in[11];

    int n_ent = in_sizes[0] / HDIM;
    int n_edges = in_sizes[9];
    int ntiles = (n_ent + TILE - 1) / TILE;
    int nbuckets = ntiles * NREL;

    char* ws = (char*)d_ws;
    size_t wo = 0;
    auto alloc = [&](size_t bytes) {
        void* p = ws + wo;
        wo = (wo + bytes + 255) & ~(size_t)255;
        return p;
    };
    int* cnt    = (int*)alloc((size_t)nbuckets * 4);
    int* off    = (int*)alloc((size_t)(nbuckets + 1) * 4);
    int* curp   = (int*)alloc((size_t)nbuckets * 4);
    short* wt1  = (short*)alloc((size_t)NREL * HDIM * HDIM * 2);
    short* wt2  = (short*)alloc((size_t)NREL * HDIM * HDIM * 2);
    short* lw1T = (short*)alloc((size_t)HDIM * HDIM * 2);
    short* lw2T = (short*)alloc((size_t)HDIM * HDIM * 2);
    short* h0   = (short*)alloc((size_t)n_ent * HDIM * 2);
    short* h1   = (short*)alloc((size_t)n_ent * HDIM * 2);
    int* edge_s = (int*)alloc((size_t)n_edges * 4);

    // weight prep + input cast
    compute_wt<<<NREL * HDIM, HDIM, 0, stream>>>(basis1, wc1, wt1);
    compute_wt<<<NREL * HDIM, HDIM, 0, stream>>>(basis2, wc2, wt2);
    transpose128<<<HDIM, HDIM, 0, stream>>>(lw1, lw1T);
    transpose128<<<HDIM, HDIM, 0, stream>>>(lw2, lw2T);
    cast_bf16<<<512, 256, 0, stream>>>(emb, h0, n_ent * HDIM / 4);

    // bucket sort (once; reused by both layers)
    zero_i32<<<(nbuckets + 255) / 256, 256, 0, stream>>>(cnt, nbuckets);
    hist_b<<<1024, 256, 0, stream>>>(dst, rel, n_edges, cnt);
    scan_b<<<1, 1024, 0, stream>>>(cnt, nbuckets, off, curp);
    scatter_b<<<1024, 256, 0, stream>>>(src, dst, rel, n_edges, curp, edge_s);

    // fused layers: zero global atomics, single store per output element
    rgcn_layer<<<ntiles, NTHREADS, 0, stream>>>(h0, wt1, lw1T, bias1, off, edge_s,
                                                h1, nullptr, n_ent);
    rgcn_layer<<<ntiles, NTHREADS, 0, stream>>>(h1, wt2, lw2T, bias2, off, edge_s,
                                                nullptr, (float*)d_out, n_ent);
}

// Round 4
// 671.179 us; speedup vs baseline: 2.6844x; 2.6844x over previous
//
#include <hip/hip_runtime.h>
#include <hip/hip_bf16.h>

#define HDIM 128
#define NREL 16
#define NBASES 8
#define KSLOTS 17            // 16 relations + self-loop
#define KDIM (KSLOTS * HDIM) // 2176
#define LDSA 136             // bf16 LDS row stride (128+8): 2-way bank alias (free)
#define CHCAP 32768          // AGG chunk rows cap: 142MB stays L3-resident

typedef short bf16x8 __attribute__((ext_vector_type(8)));
typedef short s16x4 __attribute__((ext_vector_type(4)));
typedef float f32x4 __attribute__((ext_vector_type(4)));

static __device__ __forceinline__ short f2bf(float x) {
    __hip_bfloat16 b = __float2bfloat16(x);
    return *(short*)&b;
}
static __device__ __forceinline__ float bf2f(short u) {
    unsigned v = ((unsigned)(unsigned short)u) << 16;
    return __uint_as_float(v);
}

// ---------------- weight prep ----------------
// wtL[o][r*128+i] = W_r[i][o] = sum_b wcomp[r][b]*basis[b][i][o]   (bf16)
__global__ void compute_wt(const float* __restrict__ basis,
                           const float* __restrict__ wcomp,
                           short* __restrict__ wtL) {
    int ro = blockIdx.x;
    int r = ro >> 7, o = ro & 127;
    int i = threadIdx.x;
    float acc = 0.f;
#pragma unroll
    for (int b = 0; b < NBASES; ++b)
        acc += wcomp[r * NBASES + b] * basis[(b * HDIM + i) * HDIM + o];
    wtL[(size_t)o * KDIM + r * HDIM + i] = f2bf(acc);
}

// wtL[o][2048+i] = loop_w[i][o]
__global__ void transposeL(const float* __restrict__ in, short* __restrict__ wtL) {
    int o = blockIdx.x, i = threadIdx.x;
    wtL[(size_t)o * KDIM + NREL * HDIM + i] = f2bf(in[i * HDIM + o]);
}

// fp32 -> bf16 cast (vectorized)
__global__ void cast_bf16(const float* __restrict__ in, short* __restrict__ out, int n4) {
    for (int i = blockIdx.x * blockDim.x + threadIdx.x; i < n4; i += gridDim.x * blockDim.x) {
        f32x4 v = ((const f32x4*)in)[i];
        s16x4 o;
#pragma unroll
        for (int j = 0; j < 4; ++j) o[j] = f2bf(v[j]);
        ((s16x4*)out)[i] = o;
    }
}

__global__ void zero_i32(int* __restrict__ p, int n) {
    int i = blockIdx.x * blockDim.x + threadIdx.x;
    if (i < n) p[i] = 0;
}

// ---------------- counting sort by key = dst*16 + rel (800K bins) ----------------
__global__ __launch_bounds__(256) void hist_k(const int* __restrict__ dst,
                                              const int* __restrict__ rel, int n,
                                              int* __restrict__ hist) {
    for (int i = blockIdx.x * blockDim.x + threadIdx.x; i < n; i += gridDim.x * blockDim.x)
        atomicAdd(&hist[dst[i] * NREL + rel[i]], 1);
}

// per-block exclusive scan (1024 elems) + block totals
__global__ __launch_bounds__(1024) void scan_p1(const int* __restrict__ hist, int n,
                                                int* __restrict__ off, int* __restrict__ part) {
    __shared__ int sh[1024];
    int t = threadIdx.x, b = blockIdx.x;
    int i = b * 1024 + t;
    int x = (i < n) ? hist[i] : 0;
    sh[t] = x;
    __syncthreads();
    for (int d = 1; d < 1024; d <<= 1) {
        int v = sh[t];
        int u = (t >= d) ? sh[t - d] : 0;
        __syncthreads();
        sh[t] = v + u;
        __syncthreads();
    }
    if (i < n) off[i] = sh[t] - x;
    if (t == 1023) part[b] = sh[t];
}

// exclusive scan of block totals (single block)
__global__ __launch_bounds__(1024) void scan_p2(int* __restrict__ part, int nb) {
    __shared__ int sh[1024];
    int t = threadIdx.x;
    int x = (t < nb) ? part[t] : 0;
    sh[t] = x;
    __syncthreads();
    for (int d = 1; d < 1024; d <<= 1) {
        int v = sh[t];
        int u = (t >= d) ? sh[t - d] : 0;
        __syncthreads();
        sh[t] = v + u;
        __syncthreads();
    }
    if (t < nb) part[t] = sh[t] - x;
}

// add block offsets back; copy to cur
__global__ __launch_bounds__(1024) void scan_p3(int* __restrict__ off, const int* __restrict__ part,
                                                int n, int nk, int* __restrict__ cur) {
    int i = blockIdx.x * 1024 + threadIdx.x;
    if (i < n) {
        int v = off[i] + part[blockIdx.x];
        off[i] = v;
        if (i < nk) cur[i] = v;
    }
}

// place edges: edge2[p] = src | rel<<16  (n_ent < 65536)
__global__ __launch_bounds__(256) void scatter_k(const int* __restrict__ src,
                                                 const int* __restrict__ dst,
                                                 const int* __restrict__ rel, int n,
                                                 int* __restrict__ cur,
                                                 int* __restrict__ edge2) {
    for (int i = blockIdx.x * blockDim.x + threadIdx.x; i < n; i += gridDim.x * blockDim.x) {
        int k = dst[i] * NREL + rel[i];
        int p = atomicAdd(&cur[k], 1);
        edge2[p] = (src[i] & 0xFFFF) | (rel[i] << 16);
    }
}

// ---------------- AGG build: barrier-free streaming gather ----------------
// Group = 16 lanes per (dst row, rel-half). Each group reads its ~8 edges
// (contiguous in key-sorted edge2), issues ALL h[src] gathers up-front
// (batch-8 ILP), accumulates fp32 in registers, writes each of its 8 AGG
// slots exactly once (zeros for empty slots). rh-half==1 also writes
// slot 16 = h[d] (self-loop). No barriers, no atomics, no memset.
__global__ __launch_bounds__(256) void agg_build(
    const short* __restrict__ h,
    const int* __restrict__ off,     // [NK+1], key-sorted offsets
    const int* __restrict__ edge2,   // src | rel<<16
    short* __restrict__ AGG,         // [rows][17][128] bf16
    int c0, int rows) {
    int tid = threadIdx.x;
    int grp = blockIdx.x * 16 + (tid >> 4);
    int lane16 = tid & 15;
    int lane = tid & 63;
    int gb = lane & 48;              // 16-lane group base within wave
    int drow = grp >> 1;
    if (drow >= rows) return;
    int rh = (grp & 1) * 8;
    int d = c0 + drow;
    int kbase = d * NREL + rh;

    int e0 = off[kbase];
    int e1 = off[kbase + 8];
    int deg = e1 - e0;

    int pkv = (e0 + lane16 < e1) ? edge2[e0 + lane16] : 0;

    bf16x8 va[8];
    int rlv[8];
#pragma unroll
    for (int p = 0; p < 8; ++p) {
        int pk = __shfl(pkv, gb + p);
        rlv[p] = ((pk >> 16) & 15) - rh;
        const short* hp = h + (size_t)(pk & 0xFFFF) * HDIM + lane16 * 8;
        va[p] = (p < deg) ? *(const bf16x8*)hp : (bf16x8)0;
    }

    float acc[8] = {0.f, 0.f, 0.f, 0.f, 0.f, 0.f, 0.f, 0.f};
    int rl = 0;
    short* outp = AGG + ((size_t)drow * KSLOTS + rh) * HDIM + lane16 * 8;

    auto flushTo = [&](int rt) {
        while (rl < rt) {
            bf16x8 o;
#pragma unroll
            for (int c = 0; c < 8; ++c) { o[c] = f2bf(acc[c]); acc[c] = 0.f; }
            *(bf16x8*)(outp + rl * HDIM) = o;
            ++rl;
        }
    };

#pragma unroll
    for (int p = 0; p < 8; ++p) {
        if (p < deg) {
            flushTo(rlv[p]);
#pragma unroll
            for (int c = 0; c < 8; ++c) acc[c] += bf2f(va[p][c]);
        }
    }
    // rare tail: deg > 8 (Poisson(8) upper tail)
    for (int e = e0 + 8; e < e1; ++e) {
        int pk = edge2[e];
        flushTo(((pk >> 16) & 15) - rh);
        bf16x8 v = *(const bf16x8*)(h + (size_t)(pk & 0xFFFF) * HDIM + lane16 * 8);
#pragma unroll
        for (int c = 0; c < 8; ++c) acc[c] += bf2f(v[c]);
    }
    flushTo(8);

    if (rh) {  // self-loop slot 16 (outp currently points at slot 8)
        bf16x8 v = *(const bf16x8*)(h + (size_t)d * HDIM + lane16 * 8);
        *(bf16x8*)(outp + 8 * HDIM) = v;
    }
}

// ---------------- dense GEMM: out = relu(AGG @ WstackT + bias) ----------------
// Block = 64 rows x 128 cols, 256 threads (4 waves, wave tile 32x64).
// K = 2176 (17 slots of 128). B (wtL, 557KB) stays L2-hot. 17.4KB LDS ->
// high block-occupancy ceiling; 782 blocks full-size (vs 391 at 128-row).
__global__ __launch_bounds__(256) void agg_gemm(
    const short* __restrict__ AGG,   // [rows][17][128] bf16
    const short* __restrict__ wtL,   // [128 o][2176 k] bf16
    const float* __restrict__ bias,  // [128]
    short* __restrict__ out_bf,      // layer-1 output (bf16) or nullptr
    float* __restrict__ out_f,       // layer-2 output (fp32) or nullptr
    int c0, int rows) {
    __shared__ short As[64 * LDSA];
    int tid = threadIdx.x;
    int row0 = blockIdx.x * 64;
    if (row0 >= rows) return;
    int wave = tid >> 6, lane = tid & 63;
    int mq = (wave & 1) * 32, nq = (wave >> 1) * 64;
    int lr = lane & 15, quad = lane >> 4;
    int r2 = tid >> 2, ch = tid & 3;   // staging: row r2, 32-col quarter ch

    f32x4 acc[2][4] = {};

    for (int ks = 0; ks < KSLOTS; ++ks) {
        // stage A: 64 rows x 128 cols of slot ks (4 x 16B per thread)
        {
            bool ok = (row0 + r2) < rows;
            const short* sp = AGG + ((size_t)(row0 + r2) * KSLOTS + ks) * HDIM + ch * 32;
            short* dp = As + r2 * LDSA + ch * 32;
#pragma unroll
            for (int j = 0; j < 4; ++j) {
                bf16x8 v = ok ? *(const bf16x8*)(sp + j * 8) : (bf16x8)0;
                *(bf16x8*)(dp + j * 8) = v;
            }
        }
        __syncthreads();
#pragma unroll
        for (int kk = 0; kk < 4; ++kk) {
            int kb = kk * 32 + quad * 8;
            bf16x8 a[2], b[4];
#pragma unroll
            for (int mi = 0; mi < 2; ++mi)
                a[mi] = *(const bf16x8*)(As + (mq + mi * 16 + lr) * LDSA + kb);
#pragma unroll
            for (int ni = 0; ni < 4; ++ni)
                b[ni] = *(const bf16x8*)(wtL + (size_t)(nq + ni * 16 + lr) * KDIM + ks * HDIM + kb);
#pragma unroll
            for (int mi = 0; mi < 2; ++mi)
#pragma unroll
                for (int ni = 0; ni < 4; ++ni)
                    acc[mi][ni] = __builtin_amdgcn_mfma_f32_16x16x32_bf16(a[mi], b[ni], acc[mi][ni], 0, 0, 0);
        }
        __syncthreads();
    }

    // epilogue: bias + relu, single store.  C/D: col=lane&15, row=quad*4+reg [m89]
#pragma unroll
    for (int mi = 0; mi < 2; ++mi) {
#pragma unroll
        for (int reg = 0; reg < 4; ++reg) {
            int g = row0 + mq + mi * 16 + quad * 4 + reg;
            if (g < rows) {
                size_t gd = (size_t)(c0 + g) * HDIM;
#pragma unroll
                for (int ni = 0; ni < 4; ++ni) {
                    int n = nq + ni * 16 + lr;
                    float v = acc[mi][ni][reg] + bias[n];
                    v = v > 0.f ? v : 0.f;
                    if (out_bf) out_bf[gd + n] = f2bf(v);
                    else        out_f[gd + n] = v;
                }
            }
        }
    }
}

extern "C" void kernel_launch(void* const* d_in, const int* in_sizes, int n_in,
                              void* d_out, int out_size, void* d_ws, size_t ws_size,
                              hipStream_t stream) {
    const float* emb    = (const float*)d_in[0];
    const float* basis1 = (const float*)d_in[1];
    const float* wc1    = (const float*)d_in[2];
    const float* lw1    = (const float*)d_in[3];
    const float* bias1  = (const float*)d_in[4];
    const float* basis2 = (const float*)d_in[5];
    const float* wc2    = (const float*)d_in[6];
    const float* lw2    = (const float*)d_in[7];
    const float* bias2  = (const float*)d_in[8];
    const int* src = (const int*)d_in[9];
    const int* dst = (const int*)d_in[10];
    const int* rel = (const int*)d_in[11];

    int n_ent = in_sizes[0] / HDIM;
    int n_edges = in_sizes[9];
    int NK = n_ent * NREL;
    int NK1 = NK + 1;

    char* ws = (char*)d_ws;
    size_t wo = 0;
    auto alloc = [&](size_t bytes) {
        void* p = ws + wo;
        wo = (wo + bytes + 255) & ~(size_t)255;
        return p;
    };
    int* hist  = (int*)alloc((size_t)NK1 * 4);
    int* off   = (int*)alloc((size_t)NK1 * 4);
    int* cur   = (int*)alloc((size_t)NK * 4);
    int* part  = (int*)alloc(4096);
    int* edge2 = (int*)alloc((size_t)n_edges * 4);
    short* wtL1 = (short*)alloc((size_t)HDIM * KDIM * 2);
    short* wtL2 = (short*)alloc((size_t)HDIM * KDIM * 2);
    short* h0   = (short*)alloc((size_t)n_ent * HDIM * 2);
    short* h1   = (short*)alloc((size_t)n_ent * HDIM * 2);

    // AGG: chunked. Cap at CHCAP rows (142MB) so a chunk written by agg_build
    // is still L3-resident when agg_gemm streams it back (no HBM round-trip);
    // shrink further if workspace is smaller.
    size_t rowBytes = (size_t)KSLOTS * HDIM * 2;      // 4352 B
    size_t avail = (ws_size > wo + rowBytes * 128) ? (ws_size - wo) : rowBytes * 128;
    int CH = (int)(avail / rowBytes);
    if (CH > CHCAP) CH = CHCAP;
    if (CH > n_ent) CH = n_ent;
    CH = (CH + 127) & ~127;          // multiple of 128
    if (CH < 128) CH = 128;
    while ((size_t)CH * rowBytes > avail && CH > 128) CH -= 128;
    short* AGG = (short*)alloc((size_t)CH * rowBytes);

    // weight prep + input cast
    compute_wt<<<NREL * HDIM, HDIM, 0, stream>>>(basis1, wc1, wtL1);
    compute_wt<<<NREL * HDIM, HDIM, 0, stream>>>(basis2, wc2, wtL2);
    transposeL<<<HDIM, HDIM, 0, stream>>>(lw1, wtL1);
    transposeL<<<HDIM, HDIM, 0, stream>>>(lw2, wtL2);
    cast_bf16<<<512, 256, 0, stream>>>(emb, h0, n_ent * HDIM / 4);

    // counting sort by key = dst*16+rel (once; reused by both layers)
    zero_i32<<<(NK1 + 255) / 256, 256, 0, stream>>>(hist, NK1);
    hist_k<<<1024, 256, 0, stream>>>(dst, rel, n_edges, hist);
    int nsb = (NK1 + 1023) / 1024;
    scan_p1<<<nsb, 1024, 0, stream>>>(hist, NK1, off, part);
    scan_p2<<<1, 1024, 0, stream>>>(part, nsb);
    scan_p3<<<nsb, 1024, 0, stream>>>(off, part, NK1, NK, cur);
    scatter_k<<<1024, 256, 0, stream>>>(src, dst, rel, n_edges, cur, edge2);

    // layer 1: h1 = relu([agg|h0] @ Wstack1 + b1)   (bf16 out)
    for (int c0 = 0; c0 < n_ent; c0 += CH) {
        int rows = n_ent - c0 < CH ? n_ent - c0 : CH;
        agg_build<<<(rows * 2 + 15) / 16, 256, 0, stream>>>(h0, off, edge2, AGG, c0, rows);
        agg_gemm<<<(rows + 63) / 64, 256, 0, stream>>>(AGG, wtL1, bias1, h1, nullptr, c0, rows);
    }
    // layer 2: out = relu([agg|h1] @ Wstack2 + b2)  (fp32 out)
    for (int c0 = 0; c0 < n_ent; c0 += CH) {
        int rows = n_ent - c0 < CH ? n_ent - c0 : CH;
        agg_build<<<(rows * 2 + 15) / 16, 256, 0, stream>>>(h1, off, edge2, AGG, c0, rows);
        agg_gemm<<<(rows + 63) / 64, 256, 0, stream>>>(AGG, wtL2, bias2, nullptr, (float*)d_out, c0, rows);
    }
}

// Round 5
// 502.312 us; speedup vs baseline: 3.5868x; 1.3362x over previous
//
#include <hip/hip_runtime.h>
#include <hip/hip_bf16.h>

#define HDIM 128
#define NREL 16
#define NBASES 8
#define KSLOTS 17            // 16 relations + self-loop (weights only; AGG stores 16)
#define KDIM (KSLOTS * HDIM) // 2176
#define LDSA 136             // bf16 LDS row stride (128+8)

typedef short bf16x8 __attribute__((ext_vector_type(8)));
typedef short s16x4 __attribute__((ext_vector_type(4)));
typedef float f32x4 __attribute__((ext_vector_type(4)));

static __device__ __forceinline__ short f2bf(float x) {
    __hip_bfloat16 b = __float2bfloat16(x);
    return *(short*)&b;
}
static __device__ __forceinline__ float bf2f(short u) {
    unsigned v = ((unsigned)(unsigned short)u) << 16;
    return __uint_as_float(v);
}

// ---------------- weight prep ----------------
// wtL[o][r*128+i] = W_r[i][o] = sum_b wcomp[r][b]*basis[b][i][o]   (bf16)
__global__ void compute_wt(const float* __restrict__ basis,
                           const float* __restrict__ wcomp,
                           short* __restrict__ wtL) {
    int ro = blockIdx.x;
    int r = ro >> 7, o = ro & 127;
    int i = threadIdx.x;
    float acc = 0.f;
#pragma unroll
    for (int b = 0; b < NBASES; ++b)
        acc += wcomp[r * NBASES + b] * basis[(b * HDIM + i) * HDIM + o];
    wtL[(size_t)o * KDIM + r * HDIM + i] = f2bf(acc);
}

// wtL[o][2048+i] = loop_w[i][o]
__global__ void transposeL(const float* __restrict__ in, short* __restrict__ wtL) {
    int o = blockIdx.x, i = threadIdx.x;
    wtL[(size_t)o * KDIM + NREL * HDIM + i] = f2bf(in[i * HDIM + o]);
}

// fp32 -> bf16 cast (vectorized)
__global__ void cast_bf16(const float* __restrict__ in, short* __restrict__ out, int n4) {
    for (int i = blockIdx.x * blockDim.x + threadIdx.x; i < n4; i += gridDim.x * blockDim.x) {
        f32x4 v = ((const f32x4*)in)[i];
        s16x4 o;
#pragma unroll
        for (int j = 0; j < 4; ++j) o[j] = f2bf(v[j]);
        ((s16x4*)out)[i] = o;
    }
}

__global__ void zero_i32(int* __restrict__ p, int n) {
    int i = blockIdx.x * blockDim.x + threadIdx.x;
    if (i < n) p[i] = 0;
}

// ---------------- counting sort by key = dst*16 + rel (800K bins) ----------------
__global__ __launch_bounds__(256) void hist_k(const int* __restrict__ dst,
                                              const int* __restrict__ rel, int n,
                                              int* __restrict__ hist) {
    for (int i = blockIdx.x * blockDim.x + threadIdx.x; i < n; i += gridDim.x * blockDim.x)
        atomicAdd(&hist[dst[i] * NREL + rel[i]], 1);
}

__global__ __launch_bounds__(1024) void scan_p1(const int* __restrict__ hist, int n,
                                                int* __restrict__ off, int* __restrict__ part) {
    __shared__ int sh[1024];
    int t = threadIdx.x, b = blockIdx.x;
    int i = b * 1024 + t;
    int x = (i < n) ? hist[i] : 0;
    sh[t] = x;
    __syncthreads();
    for (int d = 1; d < 1024; d <<= 1) {
        int v = sh[t];
        int u = (t >= d) ? sh[t - d] : 0;
        __syncthreads();
        sh[t] = v + u;
        __syncthreads();
    }
    if (i < n) off[i] = sh[t] - x;
    if (t == 1023) part[b] = sh[t];
}

__global__ __launch_bounds__(1024) void scan_p2(int* __restrict__ part, int nb) {
    __shared__ int sh[1024];
    int t = threadIdx.x;
    int x = (t < nb) ? part[t] : 0;
    sh[t] = x;
    __syncthreads();
    for (int d = 1; d < 1024; d <<= 1) {
        int v = sh[t];
        int u = (t >= d) ? sh[t - d] : 0;
        __syncthreads();
        sh[t] = v + u;
        __syncthreads();
    }
    if (t < nb) part[t] = sh[t] - x;
}

__global__ __launch_bounds__(1024) void scan_p3(int* __restrict__ off, const int* __restrict__ part,
                                                int n, int nk, int* __restrict__ cur) {
    int i = blockIdx.x * 1024 + threadIdx.x;
    if (i < n) {
        int v = off[i] + part[blockIdx.x];
        off[i] = v;
        if (i < nk) cur[i] = v;
    }
}

// place edges: edge2[p] = src | rel<<16  (n_ent < 65536)
__global__ __launch_bounds__(256) void scatter_k(const int* __restrict__ src,
                                                 const int* __restrict__ dst,
                                                 const int* __restrict__ rel, int n,
                                                 int* __restrict__ cur,
                                                 int* __restrict__ edge2) {
    for (int i = blockIdx.x * blockDim.x + threadIdx.x; i < n; i += gridDim.x * blockDim.x) {
        int k = dst[i] * NREL + rel[i];
        int p = atomicAdd(&cur[k], 1);
        edge2[p] = (src[i] & 0xFFFF) | (rel[i] << 16);
    }
}

// ---------------- AGG build: barrier-free streaming gather ----------------
// Group = 16 lanes per (dst row, rel-half of 8 slots). Reads its ~8 edges
// (contiguous in key-sorted edge2), issues up to 16 h[src] gathers up-front
// (ILP batch; P(deg>16)~0.003), accumulates fp32 in regs, writes ONLY
// non-empty slots (mask bit per slot; ~37% of slots are empty -> skipped).
// No barriers, no atomics, no zero-fill.
__global__ __launch_bounds__(256) void agg_build(
    const short* __restrict__ h,
    const int* __restrict__ off,      // [NK+1], key-sorted offsets
    const int* __restrict__ edge2,    // src | rel<<16
    short* __restrict__ AGG,          // [rows][16][128] bf16 (sparse-valid by mask)
    unsigned char* __restrict__ mask, // [rows][2] bytes: bit ks = slot non-empty
    int c0, int rows) {
    int tid = threadIdx.x;
    int grp = blockIdx.x * 16 + (tid >> 4);
    int lane16 = tid & 15;
    int lane = tid & 63;
    int gb = lane & 48;               // 16-lane group base within wave
    int drow = grp >> 1;
    if (drow >= rows) return;
    int rh = (grp & 1) * 8;
    int d = c0 + drow;
    int kbase = d * NREL + rh;

    int e0 = off[kbase];
    int e1 = off[kbase + 8];
    int deg = e1 - e0;

    int pkv = (e0 + lane16 < e1) ? edge2[e0 + lane16] : 0;

    bf16x8 va[16];
    int rlv[16];
#pragma unroll
    for (int p = 0; p < 16; ++p) {
        int pk = __shfl(pkv, gb + p);
        rlv[p] = ((pk >> 16) & 15) - rh;
        const short* hp = h + (size_t)(pk & 0xFFFF) * HDIM + lane16 * 8;
        if (p < deg) va[p] = *(const bf16x8*)hp;
    }

    float acc[8];
    int cs = -1;
    unsigned mbits = 0;
    short* outp = AGG + ((size_t)drow * NREL + rh) * HDIM + lane16 * 8;

    auto emit = [&]() {
        bf16x8 o;
#pragma unroll
        for (int c = 0; c < 8; ++c) o[c] = f2bf(acc[c]);
        *(bf16x8*)(outp + cs * HDIM) = o;
        mbits |= 1u << cs;
    };
    auto take = [&](int sl, bf16x8 v) {
        if (sl != cs) {
            if (cs >= 0) emit();
            cs = sl;
#pragma unroll
            for (int c = 0; c < 8; ++c) acc[c] = 0.f;
        }
#pragma unroll
        for (int c = 0; c < 8; ++c) acc[c] += bf2f(v[c]);
    };

#pragma unroll
    for (int p = 0; p < 16; ++p)
        if (p < deg) take(rlv[p], va[p]);

    // rare tail: deg > 16
    for (int e = e0 + 16; e < e1; ++e) {
        int pk = edge2[e];
        bf16x8 v = *(const bf16x8*)(h + (size_t)(pk & 0xFFFF) * HDIM + lane16 * 8);
        take(((pk >> 16) & 15) - rh, v);
    }
    if (cs >= 0) emit();

    if (lane16 == 0) mask[(size_t)drow * 2 + (rh >> 3)] = (unsigned char)mbits;
}

// ---------------- dense GEMM: out = relu([AGG|h] @ WstackT + bias) ----------------
// Block = 64 rows x 128 cols, 256 threads (4 waves, wave-tile 32x64).
// Per slot: A (16KB) and B (32KB) staged in LDS; T14 async-stage: next slot's
// global loads are issued BEFORE this slot's MFMA, and the barrier's vmcnt
// drain lands them. Mask-empty A slots are staged as zeros with no global
// read. ks==16 (self-loop) reads h directly. 52KB LDS -> 3 blocks/CU.
__global__ __launch_bounds__(256, 3) void agg_gemm(
    const short* __restrict__ AGG,    // [rows][16][128] bf16
    const short* __restrict__ h,      // bf16 [N][128] (self-loop source)
    const short* __restrict__ wtL,    // [128 o][2176 k] bf16
    const unsigned char* __restrict__ mask, // [rows][2]
    const float* __restrict__ bias,   // [128]
    short* __restrict__ out_bf,       // layer-1 output (bf16) or nullptr
    float* __restrict__ out_f,        // layer-2 output (fp32) or nullptr
    int c0, int rows) {
    __shared__ short As[64 * LDSA];
    __shared__ short Bs[128 * LDSA];
    int tid = threadIdx.x;
    int row0 = blockIdx.x * 64;
    if (row0 >= rows) return;
    int wave = tid >> 6, lane = tid & 63;
    int mq = (wave & 1) * 32, nq = (wave >> 1) * 64;
    int lr = lane & 15, quad = lane >> 4;

    // staging maps
    int r2 = tid >> 2, ch = (tid & 3) * 32;   // A: row r2 (0..63), 32-short quarter
    int rb = tid >> 1, hb = (tid & 1) * 64;   // B: row rb (0..127), 64-short half
    bool ok = (row0 + r2) < rows;
    unsigned mk = ok ? *(const unsigned short*)(mask + (size_t)(row0 + r2) * 2) : 0;

    bf16x8 apf[4], bpf[8];

    auto loadRegs = [&](int ks) {
        const short* bp = wtL + (size_t)rb * KDIM + ks * HDIM + hb;
#pragma unroll
        for (int j = 0; j < 8; ++j) bpf[j] = *(const bf16x8*)(bp + j * 8);
        if (ks == 16) {
            const short* sp = h + (size_t)(c0 + row0 + r2) * HDIM + ch;
#pragma unroll
            for (int j = 0; j < 4; ++j) apf[j] = ok ? *(const bf16x8*)(sp + j * 8) : (bf16x8)0;
        } else if (ok && ((mk >> ks) & 1)) {
            const short* sp = AGG + ((size_t)(row0 + r2) * NREL + ks) * HDIM + ch;
#pragma unroll
            for (int j = 0; j < 4; ++j) apf[j] = *(const bf16x8*)(sp + j * 8);
        } else {
#pragma unroll
            for (int j = 0; j < 4; ++j) apf[j] = (bf16x8)0;
        }
    };
    auto writeLDS = [&]() {
        short* ad = As + r2 * LDSA + ch;
#pragma unroll
        for (int j = 0; j < 4; ++j) *(bf16x8*)(ad + j * 8) = apf[j];
        short* bd = Bs + rb * LDSA + hb;
#pragma unroll
        for (int j = 0; j < 8; ++j) *(bf16x8*)(bd + j * 8) = bpf[j];
    };

    f32x4 acc[2][4] = {};

    loadRegs(0);
    writeLDS();
    __syncthreads();

#pragma unroll 1
    for (int ks = 0; ks <= 16; ++ks) {
        if (ks < 16) loadRegs(ks + 1);   // T14: issue next slot's loads now
#pragma unroll
        for (int kk = 0; kk < 4; ++kk) {
            int kb = kk * 32 + quad * 8;
            bf16x8 a[2], b[4];
#pragma unroll
            for (int mi = 0; mi < 2; ++mi)
                a[mi] = *(const bf16x8*)(As + (mq + mi * 16 + lr) * LDSA + kb);
#pragma unroll
            for (int ni = 0; ni < 4; ++ni)
                b[ni] = *(const bf16x8*)(Bs + (nq + ni * 16 + lr) * LDSA + kb);
#pragma unroll
            for (int mi = 0; mi < 2; ++mi)
#pragma unroll
                for (int ni = 0; ni < 4; ++ni)
                    acc[mi][ni] = __builtin_amdgcn_mfma_f32_16x16x32_bf16(a[mi], b[ni], acc[mi][ni], 0, 0, 0);
        }
        __syncthreads();                 // LDS reads done; vmcnt drained (prefetch arrived)
        if (ks < 16) { writeLDS(); __syncthreads(); }
    }

    // epilogue: bias + relu, single store.  C/D: col=lane&15, row=quad*4+reg [m89]
#pragma unroll
    for (int mi = 0; mi < 2; ++mi) {
#pragma unroll
        for (int reg = 0; reg < 4; ++reg) {
            int g = row0 + mq + mi * 16 + quad * 4 + reg;
            if (g < rows) {
                size_t gd = (size_t)(c0 + g) * HDIM;
#pragma unroll
                for (int ni = 0; ni < 4; ++ni) {
                    int n = nq + ni * 16 + lr;
                    float v = acc[mi][ni][reg] + bias[n];
                    v = v > 0.f ? v : 0.f;
                    if (out_bf) out_bf[gd + n] = f2bf(v);
                    else        out_f[gd + n] = v;
                }
            }
        }
    }
}

extern "C" void kernel_launch(void* const* d_in, const int* in_sizes, int n_in,
                              void* d_out, int out_size, void* d_ws, size_t ws_size,
                              hipStream_t stream) {
    const float* emb    = (const float*)d_in[0];
    const float* basis1 = (const float*)d_in[1];
    const float* wc1    = (const float*)d_in[2];
    const float* lw1    = (const float*)d_in[3];
    const float* bias1  = (const float*)d_in[4];
    const float* basis2 = (const float*)d_in[5];
    const float* wc2    = (const float*)d_in[6];
    const float* lw2    = (const float*)d_in[7];
    const float* bias2  = (const float*)d_in[8];
    const int* src = (const int*)d_in[9];
    const int* dst = (const int*)d_in[10];
    const int* rel = (const int*)d_in[11];

    int n_ent = in_sizes[0] / HDIM;
    int n_edges = in_sizes[9];
    int NK = n_ent * NREL;
    int NK1 = NK + 1;

    char* ws = (char*)d_ws;
    size_t wo = 0;
    auto alloc = [&](size_t bytes) {
        void* p = ws + wo;
        wo = (wo + bytes + 255) & ~(size_t)255;
        return p;
    };
    int* hist  = (int*)alloc((size_t)NK1 * 4);
    int* off   = (int*)alloc((size_t)NK1 * 4);
    int* cur   = (int*)alloc((size_t)NK * 4);
    int* part  = (int*)alloc(4096);
    int* edge2 = (int*)alloc((size_t)n_edges * 4);
    short* wtL1 = (short*)alloc((size_t)HDIM * KDIM * 2);
    short* wtL2 = (short*)alloc((size_t)HDIM * KDIM * 2);
    short* h0   = (short*)alloc((size_t)n_ent * HDIM * 2);
    short* h1   = (short*)alloc((size_t)n_ent * HDIM * 2);
    unsigned char* mask = (unsigned char*)alloc((size_t)n_ent * 2);

    // AGG: single chunk if workspace allows (full = n_ent*4096B = 205MB);
    // shrink to chunked mode otherwise.
    size_t rowBytes = (size_t)NREL * HDIM * 2;   // 4096 B
    size_t avail = (ws_size > wo + rowBytes * 128) ? (ws_size - wo) : rowBytes * 128;
    int CH = (int)(avail / rowBytes);
    if (CH > n_ent) CH = n_ent;
    CH = (CH + 127) & ~127;
    if (CH < 128) CH = 128;
    while ((size_t)CH * rowBytes > avail && CH > 128) CH -= 128;
    short* AGG = (short*)alloc((size_t)CH * rowBytes);

    // weight prep + input cast
    compute_wt<<<NREL * HDIM, HDIM, 0, stream>>>(basis1, wc1, wtL1);
    compute_wt<<<NREL * HDIM, HDIM, 0, stream>>>(basis2, wc2, wtL2);
    transposeL<<<HDIM, HDIM, 0, stream>>>(lw1, wtL1);
    transposeL<<<HDIM, HDIM, 0, stream>>>(lw2, wtL2);
    cast_bf16<<<512, 256, 0, stream>>>(emb, h0, n_ent * HDIM / 4);

    // counting sort by key = dst*16+rel (once; reused by both layers)
    zero_i32<<<(NK1 + 255) / 256, 256, 0, stream>>>(hist, NK1);
    hist_k<<<1024, 256, 0, stream>>>(dst, rel, n_edges, hist);
    int nsb = (NK1 + 1023) / 1024;
    scan_p1<<<nsb, 1024, 0, stream>>>(hist, NK1, off, part);
    scan_p2<<<1, 1024, 0, stream>>>(part, nsb);
    scan_p3<<<nsb, 1024, 0, stream>>>(off, part, NK1, NK, cur);
    scatter_k<<<1024, 256, 0, stream>>>(src, dst, rel, n_edges, cur, edge2);

    // layer 1: h1 = relu([agg|h0] @ Wstack1 + b1)   (bf16 out)
    for (int c0 = 0; c0 < n_ent; c0 += CH) {
        int rows = n_ent - c0 < CH ? n_ent - c0 : CH;
        agg_build<<<(rows * 2 + 15) / 16, 256, 0, stream>>>(h0, off, edge2, AGG, mask, c0, rows);
        agg_gemm<<<(rows + 63) / 64, 256, 0, stream>>>(AGG, h0, wtL1, mask, bias1,
                                                       h1, nullptr, c0, rows);
    }
    // layer 2: out = relu([agg|h1] @ Wstack2 + b2)  (fp32 out)
    for (int c0 = 0; c0 < n_ent; c0 += CH) {
        int rows = n_ent - c0 < CH ? n_ent - c0 : CH;
        agg_build<<<(rows * 2 + 15) / 16, 256, 0, stream>>>(h1, off, edge2, AGG, mask, c0, rows);
        agg_gemm<<<(rows + 63) / 64, 256, 0, stream>>>(AGG, h1, wtL2, mask, bias2,
                                                       nullptr, (float*)d_out, c0, rows);
    }
}

// Round 6
// 490.821 us; speedup vs baseline: 3.6708x; 1.0234x over previous
//
#include <hip/hip_runtime.h>
#include <hip/hip_bf16.h>

#define HDIM 128
#define NREL 16
#define NBASES 8
#define KSLOTS 17            // 16 relations + self-loop (weights only; AGG stores 16)
#define KDIM (KSLOTS * HDIM) // 2176

typedef short bf16x8 __attribute__((ext_vector_type(8)));
typedef short s16x4 __attribute__((ext_vector_type(4)));
typedef float f32x4 __attribute__((ext_vector_type(4)));

static __device__ __forceinline__ short f2bf(float x) {
    __hip_bfloat16 b = __float2bfloat16(x);
    return *(short*)&b;
}
static __device__ __forceinline__ float bf2f(short u) {
    unsigned v = ((unsigned)(unsigned short)u) << 16;
    return __uint_as_float(v);
}

// ---------------- weight prep ----------------
// wtL[o][r*128+i] = W_r[i][o] = sum_b wcomp[r][b]*basis[b][i][o]   (bf16)
__global__ void compute_wt(const float* __restrict__ basis,
                           const float* __restrict__ wcomp,
                           short* __restrict__ wtL) {
    int ro = blockIdx.x;
    int r = ro >> 7, o = ro & 127;
    int i = threadIdx.x;
    float acc = 0.f;
#pragma unroll
    for (int b = 0; b < NBASES; ++b)
        acc += wcomp[r * NBASES + b] * basis[(b * HDIM + i) * HDIM + o];
    wtL[(size_t)o * KDIM + r * HDIM + i] = f2bf(acc);
}

// wtL[o][2048+i] = loop_w[i][o]
__global__ void transposeL(const float* __restrict__ in, short* __restrict__ wtL) {
    int o = blockIdx.x, i = threadIdx.x;
    wtL[(size_t)o * KDIM + NREL * HDIM + i] = f2bf(in[i * HDIM + o]);
}

// fp32 -> bf16 cast (vectorized)
__global__ void cast_bf16(const float* __restrict__ in, short* __restrict__ out, int n4) {
    for (int i = blockIdx.x * blockDim.x + threadIdx.x; i < n4; i += gridDim.x * blockDim.x) {
        f32x4 v = ((const f32x4*)in)[i];
        s16x4 o;
#pragma unroll
        for (int j = 0; j < 4; ++j) o[j] = f2bf(v[j]);
        ((s16x4*)out)[i] = o;
    }
}

__global__ void zero_i32(int* __restrict__ p, int n) {
    int i = blockIdx.x * blockDim.x + threadIdx.x;
    if (i < n) p[i] = 0;
}

// ---------------- counting sort by key = dst*16 + rel (800K bins) ----------------
__global__ __launch_bounds__(256) void hist_k(const int* __restrict__ dst,
                                              const int* __restrict__ rel, int n,
                                              int* __restrict__ hist) {
    for (int i = blockIdx.x * blockDim.x + threadIdx.x; i < n; i += gridDim.x * blockDim.x)
        atomicAdd(&hist[dst[i] * NREL + rel[i]], 1);
}

__global__ __launch_bounds__(1024) void scan_p1(const int* __restrict__ hist, int n,
                                                int* __restrict__ off, int* __restrict__ part) {
    __shared__ int sh[1024];
    int t = threadIdx.x, b = blockIdx.x;
    int i = b * 1024 + t;
    int x = (i < n) ? hist[i] : 0;
    sh[t] = x;
    __syncthreads();
    for (int d = 1; d < 1024; d <<= 1) {
        int v = sh[t];
        int u = (t >= d) ? sh[t - d] : 0;
        __syncthreads();
        sh[t] = v + u;
        __syncthreads();
    }
    if (i < n) off[i] = sh[t] - x;
    if (t == 1023) part[b] = sh[t];
}

__global__ __launch_bounds__(1024) void scan_p2(int* __restrict__ part, int nb) {
    __shared__ int sh[1024];
    int t = threadIdx.x;
    int x = (t < nb) ? part[t] : 0;
    sh[t] = x;
    __syncthreads();
    for (int d = 1; d < 1024; d <<= 1) {
        int v = sh[t];
        int u = (t >= d) ? sh[t - d] : 0;
        __syncthreads();
        sh[t] = v + u;
        __syncthreads();
    }
    if (t < nb) part[t] = sh[t] - x;
}

__global__ __launch_bounds__(1024) void scan_p3(int* __restrict__ off, const int* __restrict__ part,
                                                int n, int nk, int* __restrict__ cur) {
    int i = blockIdx.x * 1024 + threadIdx.x;
    if (i < n) {
        int v = off[i] + part[blockIdx.x];
        off[i] = v;
        if (i < nk) cur[i] = v;
    }
}

// place edges: edge2[p] = src | rel<<16  (n_ent < 65536)
__global__ __launch_bounds__(256) void scatter_k(const int* __restrict__ src,
                                                 const int* __restrict__ dst,
                                                 const int* __restrict__ rel, int n,
                                                 int* __restrict__ cur,
                                                 int* __restrict__ edge2) {
    for (int i = blockIdx.x * blockDim.x + threadIdx.x; i < n; i += gridDim.x * blockDim.x) {
        int k = dst[i] * NREL + rel[i];
        int p = atomicAdd(&cur[k], 1);
        edge2[p] = (src[i] & 0xFFFF) | (rel[i] << 16);
    }
}

// ---------------- AGG build: barrier-free streaming gather ----------------
// Group = 16 lanes per (dst row, 8-slot rel-half). Edges of the 8 slots are
// contiguous in key-sorted edge2. Per slot classification (u16 srcs code):
//   0xFFFF = empty; 0xFFFE = multi-edge (aggregate written to AGG);
//   else   = the single edge's src id (NO gather, NO AGG write: gemm reads h).
// A deg-1 slot at the reg-window boundary safely degrades to multi.
// Multi slots: gathers issued up-front (ILP), fp32 reg accumulate, one
// bf16 row written per slot. No barriers, no atomics, no zero-fill.
__global__ __launch_bounds__(256) void agg_build(
    const short* __restrict__ h,
    const int* __restrict__ off,      // [NK+1], key-sorted offsets
    const int* __restrict__ edge2,    // src | rel<<16
    short* __restrict__ AGG,          // [rows][16][128] bf16 (valid where srcs==0xFFFE)
    unsigned short* __restrict__ srcs,// [rows][16] slot codes
    int c0, int rows) {
    int tid = threadIdx.x;
    int grp = blockIdx.x * 16 + (tid >> 4);
    int lane16 = tid & 15;
    int lane = tid & 63;
    int gb = lane & 48;               // 16-lane group base within wave
    int drow = grp >> 1;
    if (drow >= rows) return;
    int rh = (grp & 1) * 8;
    int d = c0 + drow;
    int kbase = d * NREL + rh;

    int e0 = off[kbase];
    int e8 = off[kbase + 8];
    int deg = e8 - e0;

    int pkv = (e0 + lane16 < e8) ? edge2[e0 + lane16] : 0;

    int rlv[17], srcv[16];
#pragma unroll
    for (int p = 0; p < 16; ++p) {
        int pk = __shfl(pkv, gb + p);
        rlv[p] = (p < deg) ? (((pk >> 16) & 15) - rh) : 255;
        srcv[p] = pk & 0xFFFF;
    }
    // forbid "single" at the window edge when a tail exists
    rlv[16] = (deg > 16) ? rlv[15] : 255;

    bool single[16];
#pragma unroll
    for (int p = 0; p < 16; ++p)
        single[p] = ((p == 0) || (rlv[p - 1] != rlv[p])) && (rlv[p + 1] != rlv[p]);

    // gather only multi-slot edges
    bf16x8 va[16];
#pragma unroll
    for (int p = 0; p < 16; ++p)
        if (p < deg && !single[p])
            va[p] = *(const bf16x8*)(h + (size_t)srcv[p] * HDIM + lane16 * 8);

    // slot code: lane l (<8) owns slot l of this half
    unsigned short val = 0xFFFF;
#pragma unroll
    for (int p = 0; p < 16; ++p)
        if (p < deg && rlv[p] == lane16)
            val = single[p] ? (unsigned short)srcv[p] : (unsigned short)0xFFFE;

    float acc[8] = {0.f, 0.f, 0.f, 0.f, 0.f, 0.f, 0.f, 0.f};
    int cs = -1;
    short* outp = AGG + ((size_t)drow * NREL + rh) * HDIM + lane16 * 8;

    auto emit = [&]() {
        bf16x8 o;
#pragma unroll
        for (int c = 0; c < 8; ++c) o[c] = f2bf(acc[c]);
        *(bf16x8*)(outp + cs * HDIM) = o;
    };
    auto take = [&](int sl, bf16x8 v) {
        if (sl != cs) {
            if (cs >= 0) emit();
            cs = sl;
#pragma unroll
            for (int c = 0; c < 8; ++c) acc[c] = 0.f;
        }
#pragma unroll
        for (int c = 0; c < 8; ++c) acc[c] += bf2f(v[c]);
    };

#pragma unroll
    for (int p = 0; p < 16; ++p)
        if (p < deg && !single[p]) take(rlv[p], va[p]);

    // rare tail: deg > 16 (Poisson(8) upper tail, ~0.4% of groups)
    for (int e = e0 + 16; e < e8; ++e) {
        int pk = edge2[e];
        int sl = ((pk >> 16) & 15) - rh;
        if (sl == lane16) val = 0xFFFE;
        bf16x8 v = *(const bf16x8*)(h + (size_t)(pk & 0xFFFF) * HDIM + lane16 * 8);
        take(sl, v);
    }
    if (cs >= 0) emit();

    if (lane16 < 8) srcs[(size_t)drow * NREL + rh + lane16] = val;
}

// ---------------- dense GEMM: out = relu([AGG|h] @ WstackT + bias) ----------------
// Block = 64 rows x 128 cols, 256 threads (4 waves, wave-tile 32x64).
// Per slot: A (16KB) + B (32KB) in LDS, T2 XOR-swizzled (chunk16 ^= row&7,
// same involution on write and read -> conflict-free). T14 async-stage:
// next slot's global loads issue before this slot's MFMA; the barrier's
// vmcnt drain lands them. A-source per row-slot from srcs code:
// empty -> zeros (no read); single -> h[src] (hot); multi -> AGG row.
// ks==16 self-loop reads h[own row]. 48KB LDS -> 3 blocks/CU.
__global__ __launch_bounds__(256, 3) void agg_gemm(
    const short* __restrict__ AGG,    // [rows][16][128] bf16
    const short* __restrict__ h,      // bf16 [N][128]
    const short* __restrict__ wtL,    // [128 o][2176 k] bf16
    const unsigned short* __restrict__ srcs, // [rows][16]
    const float* __restrict__ bias,   // [128]
    short* __restrict__ out_bf,       // layer-1 output (bf16) or nullptr
    float* __restrict__ out_f,        // layer-2 output (fp32) or nullptr
    int c0, int rows) {
    __shared__ short As[64 * HDIM];
    __shared__ short Bs[128 * HDIM];
    int tid = threadIdx.x;
    int row0 = blockIdx.x * 64;
    if (row0 >= rows) return;
    int wave = tid >> 6, lane = tid & 63;
    int mq = (wave & 1) * 32, nq = (wave >> 1) * 64;
    int lr = lane & 15, quad = lane >> 4;

    int r2 = tid >> 2, ca = tid & 3;      // A staging: row, 4x16B chunk group
    int rb = tid >> 1, cb = (tid & 1) * 8;// B staging: row, 8x16B chunk base
    bool ok = (row0 + r2) < rows;

    // preload this row's 16 slot codes (8 u32)
    unsigned wq[8];
    {
        uint4 a = make_uint4(0xFFFFFFFFu, 0xFFFFFFFFu, 0xFFFFFFFFu, 0xFFFFFFFFu);
        uint4 b = a;
        if (ok) {
            const uint4* sp = (const uint4*)(srcs + (size_t)(row0 + r2) * NREL);
            a = sp[0]; b = sp[1];
        }
        wq[0] = a.x; wq[1] = a.y; wq[2] = a.z; wq[3] = a.w;
        wq[4] = b.x; wq[5] = b.y; wq[6] = b.z; wq[7] = b.w;
    }

    bf16x8 apf[4], bpf[8];
    auto loadRegs = [&](int ks) {
        const short* bp = wtL + (size_t)rb * KDIM + ks * HDIM + cb * 8;
#pragma unroll
        for (int j = 0; j < 8; ++j) bpf[j] = *(const bf16x8*)(bp + j * 8);
        if (ks == 16) {
            if (ok) {
                const short* sp = h + (size_t)(c0 + row0 + r2) * HDIM + ca * 32;
#pragma unroll
                for (int j = 0; j < 4; ++j) apf[j] = *(const bf16x8*)(sp + j * 8);
            } else {
#pragma unroll
                for (int j = 0; j < 4; ++j) apf[j] = (bf16x8)0;
            }
        } else {
            unsigned w = 0xFFFFu;
#pragma unroll
            for (int q = 0; q < 8; ++q) if ((ks >> 1) == q) w = wq[q];
            unsigned e = (ks & 1) ? (w >> 16) : (w & 0xFFFFu);
            if (e == 0xFFFFu) {
#pragma unroll
                for (int j = 0; j < 4; ++j) apf[j] = (bf16x8)0;
            } else {
                const short* sp = (e == 0xFFFEu)
                    ? AGG + ((size_t)(row0 + r2) * NREL + ks) * HDIM + ca * 32
                    : h + (size_t)e * HDIM + ca * 32;
#pragma unroll
                for (int j = 0; j < 4; ++j) apf[j] = *(const bf16x8*)(sp + j * 8);
            }
        }
    };
    auto writeLDS = [&]() {
#pragma unroll
        for (int j = 0; j < 4; ++j) {
            int c = ca * 4 + j;
            *(bf16x8*)(As + r2 * HDIM + (c ^ (r2 & 7)) * 8) = apf[j];
        }
#pragma unroll
        for (int j = 0; j < 8; ++j) {
            int c = cb + j;
            *(bf16x8*)(Bs + rb * HDIM + (c ^ (rb & 7)) * 8) = bpf[j];
        }
    };

    f32x4 acc[2][4] = {};

    loadRegs(0);
    writeLDS();
    __syncthreads();

#pragma unroll 1
    for (int ks = 0; ks <= 16; ++ks) {
        if (ks < 16) loadRegs(ks + 1);   // T14: issue next slot's loads now
#pragma unroll
        for (int kk = 0; kk < 4; ++kk) {
            int c = kk * 4 + quad;
            bf16x8 a[2], b[4];
#pragma unroll
            for (int mi = 0; mi < 2; ++mi) {
                int row = mq + mi * 16 + lr;
                a[mi] = *(const bf16x8*)(As + row * HDIM + (c ^ (row & 7)) * 8);
            }
#pragma unroll
            for (int ni = 0; ni < 4; ++ni) {
                int row = nq + ni * 16 + lr;
                b[ni] = *(const bf16x8*)(Bs + row * HDIM + (c ^ (row & 7)) * 8);
            }
#pragma unroll
            for (int mi = 0; mi < 2; ++mi)
#pragma unroll
                for (int ni = 0; ni < 4; ++ni)
                    acc[mi][ni] = __builtin_amdgcn_mfma_f32_16x16x32_bf16(a[mi], b[ni], acc[mi][ni], 0, 0, 0);
        }
        __syncthreads();                 // LDS reads done; vmcnt drained (prefetch arrived)
        if (ks < 16) { writeLDS(); __syncthreads(); }
    }

    // epilogue: bias + relu, single store.  C/D: col=lane&15, row=quad*4+reg [m89]
#pragma unroll
    for (int mi = 0; mi < 2; ++mi) {
#pragma unroll
        for (int reg = 0; reg < 4; ++reg) {
            int g = row0 + mq + mi * 16 + quad * 4 + reg;
            if (g < rows) {
                size_t gd = (size_t)(c0 + g) * HDIM;
#pragma unroll
                for (int ni = 0; ni < 4; ++ni) {
                    int n = nq + ni * 16 + lr;
                    float v = acc[mi][ni][reg] + bias[n];
                    v = v > 0.f ? v : 0.f;
                    if (out_bf) out_bf[gd + n] = f2bf(v);
                    else        out_f[gd + n] = v;
                }
            }
        }
    }
}

extern "C" void kernel_launch(void* const* d_in, const int* in_sizes, int n_in,
                              void* d_out, int out_size, void* d_ws, size_t ws_size,
                              hipStream_t stream) {
    const float* emb    = (const float*)d_in[0];
    const float* basis1 = (const float*)d_in[1];
    const float* wc1    = (const float*)d_in[2];
    const float* lw1    = (const float*)d_in[3];
    const float* bias1  = (const float*)d_in[4];
    const float* basis2 = (const float*)d_in[5];
    const float* wc2    = (const float*)d_in[6];
    const float* lw2    = (const float*)d_in[7];
    const float* bias2  = (const float*)d_in[8];
    const int* src = (const int*)d_in[9];
    const int* dst = (const int*)d_in[10];
    const int* rel = (const int*)d_in[11];

    int n_ent = in_sizes[0] / HDIM;
    int n_edges = in_sizes[9];
    int NK = n_ent * NREL;
    int NK1 = NK + 1;

    char* ws = (char*)d_ws;
    size_t wo = 0;
    auto alloc = [&](size_t bytes) {
        void* p = ws + wo;
        wo = (wo + bytes + 255) & ~(size_t)255;
        return p;
    };
    int* hist  = (int*)alloc((size_t)NK1 * 4);
    int* off   = (int*)alloc((size_t)NK1 * 4);
    int* cur   = (int*)alloc((size_t)NK * 4);
    int* part  = (int*)alloc(4096);
    int* edge2 = (int*)alloc((size_t)n_edges * 4);
    short* wtL1 = (short*)alloc((size_t)HDIM * KDIM * 2);
    short* wtL2 = (short*)alloc((size_t)HDIM * KDIM * 2);
    short* h0   = (short*)alloc((size_t)n_ent * HDIM * 2);
    short* h1   = (short*)alloc((size_t)n_ent * HDIM * 2);
    unsigned short* srcs = (unsigned short*)alloc((size_t)n_ent * NREL * 2);

    // AGG: single chunk if workspace allows (full = n_ent*4096B = 205MB);
    // shrink to chunked mode otherwise.
    size_t rowBytes = (size_t)NREL * HDIM * 2;   // 4096 B
    size_t avail = (ws_size > wo + rowBytes * 128) ? (ws_size - wo) : rowBytes * 128;
    int CH = (int)(avail / rowBytes);
    if (CH > n_ent) CH = n_ent;
    CH = (CH + 127) & ~127;
    if (CH < 128) CH = 128;
    while ((size_t)CH * rowBytes > avail && CH > 128) CH -= 128;
    short* AGG = (short*)alloc((size_t)CH * rowBytes);

    // weight prep + input cast
    compute_wt<<<NREL * HDIM, HDIM, 0, stream>>>(basis1, wc1, wtL1);
    compute_wt<<<NREL * HDIM, HDIM, 0, stream>>>(basis2, wc2, wtL2);
    transposeL<<<HDIM, HDIM, 0, stream>>>(lw1, wtL1);
    transposeL<<<HDIM, HDIM, 0, stream>>>(lw2, wtL2);
    cast_bf16<<<512, 256, 0, stream>>>(emb, h0, n_ent * HDIM / 4);

    // counting sort by key = dst*16+rel (once; reused by both layers)
    zero_i32<<<(NK1 + 255) / 256, 256, 0, stream>>>(hist, NK1);
    hist_k<<<1024, 256, 0, stream>>>(dst, rel, n_edges, hist);
    int nsb = (NK1 + 1023) / 1024;
    scan_p1<<<nsb, 1024, 0, stream>>>(hist, NK1, off, part);
    scan_p2<<<1, 1024, 0, stream>>>(part, nsb);
    scan_p3<<<nsb, 1024, 0, stream>>>(off, part, NK1, NK, cur);
    scatter_k<<<1024, 256, 0, stream>>>(src, dst, rel, n_edges, cur, edge2);

    // layer 1: h1 = relu([agg|h0] @ Wstack1 + b1)   (bf16 out)
    for (int c0 = 0; c0 < n_ent; c0 += CH) {
        int rows = n_ent - c0 < CH ? n_ent - c0 : CH;
        agg_build<<<(rows * 2 + 15) / 16, 256, 0, stream>>>(h0, off, edge2, AGG, srcs, c0, rows);
        agg_gemm<<<(rows + 63) / 64, 256, 0, stream>>>(AGG, h0, wtL1, srcs, bias1,
                                                       h1, nullptr, c0, rows);
    }
    // layer 2: out = relu([agg|h1] @ Wstack2 + b2)  (fp32 out)
    for (int c0 = 0; c0 < n_ent; c0 += CH) {
        int rows = n_ent - c0 < CH ? n_ent - c0 : CH;
        agg_build<<<(rows * 2 + 15) / 16, 256, 0, stream>>>(h1, off, edge2, AGG, srcs, c0, rows);
        agg_gemm<<<(rows + 63) / 64, 256, 0, stream>>>(AGG, h1, wtL2, srcs, bias2,
                                                       nullptr, (float*)d_out, c0, rows);
    }
}